// Round 15
// baseline (68.184 us; speedup 1.0000x reference)
//
#include <hip/hip_runtime.h>
#include <math.h>

#define BB 8
#define NN 2000
#define CC 81
#define NCLS 80             // classes 1..80 (class 0 never valid)
#define MAXI 100
#define MCLS 128            // per-class member cap (mean ~25, sd ~5)

static constexpr float kMinConf = 0.7f;
static constexpr float kNmsThr  = 0.3f;

// ---------------- workspace layout (bytes) ----------------
// boxes : [0,      256000)   BN*4 f32 (refined, clipped)
// cls   : [256000, 320000)   BN i32   (argmax class; 0 if invalid)
// ccnt  : [320000, 322560)   8*80 i32 per-(batch,class) member count (memset 0)
// cslot : [322560, 977920)   8*80*128 u64 member keys (unordered; order fixed
//                            later by rank-sort on unique keys -> deterministic)

// key = (score_bits << 32) | ~idx. Valid scores are positive floats so u32
// compare == float compare; key desc == (score desc, idx asc) == reference's
// stable descending argsort. idx = ~(u32)key. Keys unique; 0 = "absent".
__device__ __forceinline__ unsigned long long mkey(float s, int i) {
    return ((unsigned long long)__float_as_uint(s) << 32) | (unsigned int)(~(unsigned int)i);
}

__device__ __forceinline__ bool iou_gt_thr(float4 a, float aarea, float4 t) {
    float iy1 = fmaxf(a.x, t.x), ix1 = fmaxf(a.y, t.y);
    float iy2 = fminf(a.z, t.z), ix2 = fminf(a.w, t.w);
    float inter = fmaxf(iy2 - iy1, 0.f) * fmaxf(ix2 - ix1, 0.f);
    float tarea = (t.z - t.x) * (t.w - t.y);
    float uni = fmaxf(aarea + tarea - inter, 1e-12f);
    return inter > kNmsThr * uni;
}

// ---- kA: wave-per-ROI argmax + box refine; valid ROIs bucket themselves into
// per-(batch,class) slots via spread atomics (640 counters, ~25 adds each). ----
__global__ void kA_refine(const float* __restrict__ rois,
                          const float* __restrict__ probs,
                          const float* __restrict__ deltas,
                          float* __restrict__ boxes,
                          int* __restrict__ cls,
                          int* __restrict__ ccnt,
                          unsigned long long* __restrict__ cslot,
                          float* __restrict__ outz) {
    int gtid = blockIdx.x * blockDim.x + threadIdx.x;
    if (gtid < BB * MAXI * 6) outz[gtid] = 0.f;      // pre-zero output

    int wid = gtid >> 6;                // one wave per ROI
    int l = gtid & 63;

    const float* p = probs + (size_t)wid * CC;
    float v1 = p[l];                    // l < 64 < 81 always valid
    int   i1 = l;
    int   c2 = l + 64;
    float v2 = (c2 < CC) ? p[c2] : -1.0f;   // probs in [0,1)
    float bv; int bi;
    if (v2 > v1) { bv = v2; bi = c2; } else { bv = v1; bi = i1; }

    #pragma unroll
    for (int off = 32; off; off >>= 1) {
        float ov = __shfl_xor(bv, off);
        int   oi = __shfl_xor(bi, off);
        if (ov > bv || (ov == bv && oi < bi)) { bv = ov; bi = oi; }
    }

    if (l == 0) {
        const float4 dl = *(const float4*)(deltas + ((size_t)wid * CC + bi) * 4);
        float dy = dl.x * 0.1f, dx = dl.y * 0.1f, dh = dl.z * 0.2f, dw = dl.w * 0.2f;
        const float4 r = *(const float4*)(rois + (size_t)wid * 4);
        float y1 = r.x, x1 = r.y, y2 = r.z, x2 = r.w;
        float h = y2 - y1, w = x2 - x1;
        float cy = y1 + 0.5f * h + dy * h;
        float cx = x1 + 0.5f * w + dx * w;
        float h2 = h * expf(dh);
        float w2 = w * expf(dw);
        float oy1 = fminf(fmaxf(cy - 0.5f * h2, 0.f), 1.f);
        float ox1 = fminf(fmaxf(cx - 0.5f * w2, 0.f), 1.f);
        float oy2 = fminf(fmaxf(cy + 0.5f * h2, 0.f), 1.f);
        float ox2 = fminf(fmaxf(cx + 0.5f * w2, 0.f), 1.f);
        bool valid = (bi > 0) && (bv >= kMinConf);
        float4 bx; bx.x = oy1; bx.y = ox1; bx.z = oy2; bx.w = ox2;
        ((float4*)boxes)[wid] = bx;
        cls[wid] = valid ? bi : 0;
        if (valid) {
            int b = wid / NN, i = wid - b * NN;
            int cidx = bi - 1;
            int pos = atomicAdd(&ccnt[b * NCLS + cidx], 1);
            if (pos < MCLS)
                cslot[(size_t)(b * NCLS + cidx) * MCLS + pos] = mkey(bv, i);
        }
    }
}

// ---- k2: one 1024-thread block per batch. Wave w runs classes w, w+16, ...:
// load slot list -> in-wave rank sort (validated) -> ballot-fixpoint greedy
// NMS (validated exact) -> positional keys[] in LDS. Then one barrier and the
// R14-validated histogram-threshold + candidate rank-count emit, all LDS. ----
__global__ void __launch_bounds__(1024) k2_nms_emit(
        const float* __restrict__ boxes,
        const int* __restrict__ cls,
        const int* __restrict__ ccnt,
        const unsigned long long* __restrict__ cslot,
        float* __restrict__ out) {
    const int b = blockIdx.x;
    const int tid = threadIdx.x;
    const int w = tid >> 6;             // wave 0..15
    const int l = tid & 63;

    __shared__ unsigned long long mk16[16][MCLS];    // 16 KB
    __shared__ float4 mbox16[16][64];                // 16 KB
    __shared__ ulonglong2 keys2[1024];               // 16 KB (positional by row)
    __shared__ ulonglong2 cand2[256];                //  4 KB
    __shared__ int hist[256];
    __shared__ int ccl[NCLS];
    __shared__ int Tcnt, tbsh, candn;
    unsigned long long* keys = (unsigned long long*)keys2;
    unsigned long long* cand = (unsigned long long*)cand2;

    for (int i = tid; i < 2048; i += 1024) keys[i] = 0ull;
    if (tid < NCLS) ccl[tid] = min(ccnt[b * NCLS + tid], MCLS);
    if (tid < 256) hist[tid] = 0;
    if (tid == 0) { Tcnt = 0; candn = 0; }
    __syncthreads();

    const float4* bxs = (const float4*)boxes + (size_t)b * NN;
    unsigned long long* mk = mk16[w];
    float4* mbox = mbox16[w];

    // ---- per-class NMS (no block barriers inside; waves independent) ----
    for (int k = 0; k < 5; ++k) {
        const int cidx = w + 16 * k;
        const int cnt = ccl[cidx];
        if (cnt == 0) continue;
        const unsigned long long* slot = cslot + (size_t)(b * NCLS + cidx) * MCLS;

        // load members (unordered) and in-wave stable rank sort by key desc
        unsigned long long va = (l < cnt) ? slot[l] : 0ull;
        unsigned long long vb = (64 + l < cnt) ? slot[64 + l] : 0ull;
        if (l < cnt) mk[l] = va;
        if (64 + l < cnt) mk[64 + l] = vb;
        int ra = 0, rb = 0;
        for (int t = 0; t < cnt; ++t) {
            unsigned long long kt = mk[t];           // uniform LDS broadcast
            ra += (kt > va);
            rb += (kt > vb);
        }
        if (l < cnt) mk[ra] = va;                    // lockstep: reads done
        if (64 + l < cnt) mk[rb] = vb;

        // fetch member boxes (sorted order), chunk 0 in LDS
        if (l < min(cnt, 64)) mbox[l] = bxs[(int)(~(unsigned int)mk[l])];

        // chunk 0: ballot fixpoint == greedy (validated exact)
        unsigned long long kept0 = 0ull;
        {
            bool act = (l < cnt);
            float4 a = mbox[act ? l : 0];
            float aarea = (a.z - a.x) * (a.w - a.y);
            unsigned long long colmask = 0ull;
            int tend = min(64, cnt);
            for (int t = 0; t < tend; ++t) {
                float4 tb = mbox[t];                 // uniform LDS broadcast
                if (t < l && act && iou_gt_thr(a, aarea, tb)) colmask |= (1ull << t);
            }
            unsigned long long kept = __ballot(act);
            while (true) {
                bool alive = act && ((colmask & kept) == 0ull);
                unsigned long long k2m = __ballot(alive);
                if (k2m == kept) break;
                kept = k2m;
            }
            kept0 = kept;
            bool alive = act && ((colmask & kept0) == 0ull);
            if (alive) keys[(int)(~(unsigned int)mk[l])] = mk[l];  // disjoint rows
        }
        // chunk 1 (members 64..cnt-1): astronomically rare; slow-but-correct
        if (cnt > 64) {
            int m = 64 + l;
            bool act = (m < cnt);
            unsigned long long myk = act ? mk[m] : 0ull;
            float4 a = act ? bxs[(int)(~(unsigned int)myk)]
                           : make_float4(0.f, 0.f, 0.f, 0.f);
            float aarea = (a.z - a.x) * (a.w - a.y);
            bool presup = false;
            for (int t = 0; t < 64; ++t) {
                if ((kept0 >> t) & 1ull) {
                    if (act && iou_gt_thr(a, aarea, mbox[t])) presup = true;
                }
            }
            unsigned long long colmask = 0ull;
            for (int t = 64; t < cnt; ++t) {
                float4 tb = bxs[(int)(~(unsigned int)mk[t])];   // uniform global
                if ((t - 64) < l && act && iou_gt_thr(a, aarea, tb))
                    colmask |= (1ull << (t - 64));
            }
            bool pre = act && !presup;
            unsigned long long kept = __ballot(pre);
            while (true) {
                bool alive = pre && ((colmask & kept) == 0ull);
                unsigned long long k2m = __ballot(alive);
                if (k2m == kept) break;
                kept = k2m;
            }
            bool alive = pre && ((colmask & kept) == 0ull);
            if (alive) keys[(int)(~(unsigned int)myk)] = myk;
        }
    }
    __syncthreads();

    // ---- histogram + count (keys in LDS; scores in [0.7,1) -> bucket
    // (key>>47)&0xFF is monotone in score) ----
    for (int i = tid; i < NN; i += 1024) {
        unsigned long long kv = keys[i];
        bool f = (kv != 0ull);
        if (f) atomicAdd(&hist[(int)((kv >> 47) & 0xFF)], 1);
        unsigned long long m = __ballot(f);
        if (l == 0 && m) atomicAdd(&Tcnt, __popcll(m));
    }
    __syncthreads();
    const int T = Tcnt;
    if (T == 0) return;                              // out pre-zeroed by kA

    // wave 0: threshold bucket tb (smallest b' with count(buckets >= b') >= 100)
    if (w == 0) {
        int cum = 0, tb = 0, done = 0;
        for (int chunk = 3; chunk >= 0 && !done; --chunk) {
            int bkt = chunk * 64 + (63 - l);         // lane 0 = highest bucket
            int s = hist[bkt];
            #pragma unroll
            for (int off = 1; off < 64; off <<= 1) {
                int o = __shfl_up(s, off);
                if (l >= off) s += o;
            }
            int chunktot = __shfl(s, 63);
            if (cum + chunktot >= MAXI) {
                unsigned long long m = __ballot(cum + s >= MAXI);
                int lane = __ffsll((long long)m) - 1;
                tb = chunk * 64 + (63 - lane);
                done = 1;
            } else {
                cum += chunktot;
            }
        }
        if (l == 0) tbsh = done ? tb : 0;            // T<100 -> all buckets
    }
    __syncthreads();
    const int tb = tbsh;

    // compact candidates (bucket >= tb); non-candidates have strictly smaller
    // keys, so rank among candidates == global rank. Order irrelevant.
    for (int i = tid; i < NN; i += 1024) {
        unsigned long long kv = keys[i];
        bool pr = (kv != 0ull) && ((int)((kv >> 47) & 0xFF) >= tb);
        unsigned long long m = __ballot(pr);
        int basew = 0;
        if (l == 0 && m) basew = atomicAdd(&candn, __popcll(m));
        basew = __shfl(basew, 0);
        if (pr) {
            int pos = basew + __popcll(m & ((1ull << l) - 1ull));
            if (pos < 512) cand[pos] = kv;
        }
    }
    __syncthreads();
    const int nc = candn;
    if (tid == 0 && nc < 512) cand[nc] = 0ull;       // pad for pair read
    __syncthreads();

    if (nc <= 512) {
        // rank-count among candidates (~53 uniform pair reads for nc~106)
        const int np = (nc + 1) >> 1;
        for (int s = tid; s < nc; s += 1024) {
            unsigned long long myk = cand[s];
            int r = 0;
            for (int t = 0; t < np; ++t) {
                ulonglong2 kv = cand2[t];
                r += (int)(kv.x > myk);
                r += (int)(kv.y > myk);              // pad 0 never counts
            }
            if (r < MAXI) {
                int i = (int)(~(unsigned int)myk);
                float4 bx = bxs[i];
                float* o = out + ((size_t)b * MAXI + r) * 6;
                o[0] = bx.x; o[1] = bx.y; o[2] = bx.z; o[3] = bx.w;
                o[4] = (float)cls[(size_t)b * NN + i];
                o[5] = __uint_as_float((unsigned int)(myk >> 32));
            }
        }
    } else {
        // pathological fallback: rank over all rows (zeros excluded)
        for (int s = tid; s < NN; s += 1024) {
            unsigned long long myk = keys[s];
            if (myk == 0ull) continue;
            int r = 0;
            for (int t = 0; t < 1024; ++t) {
                ulonglong2 kv = keys2[t];
                r += (int)(kv.x > myk);
                r += (int)(kv.y > myk);
            }
            if (r < MAXI) {
                int i = (int)(~(unsigned int)myk);
                float4 bx = bxs[i];
                float* o = out + ((size_t)b * MAXI + r) * 6;
                o[0] = bx.x; o[1] = bx.y; o[2] = bx.z; o[3] = bx.w;
                o[4] = (float)cls[(size_t)b * NN + i];
                o[5] = __uint_as_float((unsigned int)(myk >> 32));
            }
        }
    }
}

extern "C" void kernel_launch(void* const* d_in, const int* in_sizes, int n_in,
                              void* d_out, int out_size, void* d_ws, size_t ws_size,
                              hipStream_t stream) {
    const float* rois   = (const float*)d_in[0];
    const float* probs  = (const float*)d_in[1];
    const float* deltas = (const float*)d_in[2];
    float* outp = (float*)d_out;

    char* ws = (char*)d_ws;
    float* boxes = (float*)(ws + 0);
    int*   cls   = (int*)  (ws + 256000);
    int*   ccnt  = (int*)  (ws + 320000);
    unsigned long long* cslot = (unsigned long long*)(ws + 322560);

    hipMemsetAsync(ccnt, 0, BB * NCLS * sizeof(int), stream);
    {
        int blocks = (BB * NN * 64) / 256;   // one wave per ROI, exact
        kA_refine<<<blocks, 256, 0, stream>>>(rois, probs, deltas, boxes, cls,
                                              ccnt, cslot, outp);
    }
    {
        k2_nms_emit<<<BB, 1024, 0, stream>>>(boxes, cls, ccnt, cslot, outp);
    }
}

// Round 16
// 44.700 us; speedup vs baseline: 1.5254x; 1.5254x over previous
//
#include <hip/hip_runtime.h>
#include <math.h>

#define BB 8
#define NN 2000
#define CC 81
#define NCLS 80             // classes 1..80 (class 0 never valid)
#define MAXI 100
#define MCLS 128            // per-class member cap (mean ~25, sd ~5)

static constexpr float kMinConf = 0.7f;
static constexpr float kNmsThr  = 0.3f;

// ---------------- workspace layout (bytes) ----------------
// boxes  : [0,      256000)   BN*4 f32 (refined, clipped)
// cls    : [256000, 320000)   BN i32   (argmax class; 0 if invalid)
// ccnt   : [320000, 322560)   8*80 i32 per-(batch,class) member count (kZ zeroes)
// cslot  : [322560, 977920)   8*80*128 u64 member keys (unordered; later
//                             rank-sorted on unique keys -> deterministic)
// keysrc : [977920, 1105920)  BN u64 (kept key or 0; kA zeroes, kB writes)

// key = (score_bits << 32) | ~idx. Valid scores are positive floats so u32
// compare == float compare; key desc == (score desc, idx asc) == reference's
// stable descending argsort. idx = ~(u32)key. Keys unique; 0 = "absent".
__device__ __forceinline__ unsigned long long mkey(float s, int i) {
    return ((unsigned long long)__float_as_uint(s) << 32) | (unsigned int)(~(unsigned int)i);
}

__device__ __forceinline__ bool iou_gt_thr(float4 a, float aarea, float4 t) {
    float iy1 = fmaxf(a.x, t.x), ix1 = fmaxf(a.y, t.y);
    float iy2 = fminf(a.z, t.z), ix2 = fminf(a.w, t.w);
    float inter = fmaxf(iy2 - iy1, 0.f) * fmaxf(ix2 - ix1, 0.f);
    float tarea = (t.z - t.x) * (t.w - t.y);
    float uni = fmaxf(aarea + tarea - inter, 1e-12f);
    return inter > kNmsThr * uni;
}

// ---- kZ: zero ccnt and out (NEVER hipMemsetAsync in-graph: ~40 us/node) ----
__global__ void __launch_bounds__(1024) kZ_zero(int* __restrict__ ccnt,
                                               float* __restrict__ out) {
    int tid = threadIdx.x;
    if (tid < BB * NCLS) ccnt[tid] = 0;
    for (int i = tid; i < BB * MAXI * 6; i += 1024) out[i] = 0.f;
}

// ---- kA: wave-per-ROI argmax + box refine; valid ROIs bucket themselves into
// per-(batch,class) slots via spread atomics; zeroes keysrc. ----
__global__ void kA_refine(const float* __restrict__ rois,
                          const float* __restrict__ probs,
                          const float* __restrict__ deltas,
                          float* __restrict__ boxes,
                          int* __restrict__ cls,
                          int* __restrict__ ccnt,
                          unsigned long long* __restrict__ cslot,
                          unsigned long long* __restrict__ keysrc) {
    int gtid = blockIdx.x * blockDim.x + threadIdx.x;
    if (gtid < BB * NN) keysrc[gtid] = 0ull;

    int wid = gtid >> 6;                // one wave per ROI
    int l = gtid & 63;

    const float* p = probs + (size_t)wid * CC;
    float v1 = p[l];
    int   i1 = l;
    int   c2 = l + 64;
    float v2 = (c2 < CC) ? p[c2] : -1.0f;
    float bv; int bi;
    if (v2 > v1) { bv = v2; bi = c2; } else { bv = v1; bi = i1; }

    #pragma unroll
    for (int off = 32; off; off >>= 1) {
        float ov = __shfl_xor(bv, off);
        int   oi = __shfl_xor(bi, off);
        if (ov > bv || (ov == bv && oi < bi)) { bv = ov; bi = oi; }
    }

    if (l == 0) {
        const float4 dl = *(const float4*)(deltas + ((size_t)wid * CC + bi) * 4);
        float dy = dl.x * 0.1f, dx = dl.y * 0.1f, dh = dl.z * 0.2f, dw = dl.w * 0.2f;
        const float4 r = *(const float4*)(rois + (size_t)wid * 4);
        float y1 = r.x, x1 = r.y, y2 = r.z, x2 = r.w;
        float h = y2 - y1, w = x2 - x1;
        float cy = y1 + 0.5f * h + dy * h;
        float cx = x1 + 0.5f * w + dx * w;
        float h2 = h * expf(dh);
        float w2 = w * expf(dw);
        float oy1 = fminf(fmaxf(cy - 0.5f * h2, 0.f), 1.f);
        float ox1 = fminf(fmaxf(cx - 0.5f * w2, 0.f), 1.f);
        float oy2 = fminf(fmaxf(cy + 0.5f * h2, 0.f), 1.f);
        float ox2 = fminf(fmaxf(cx + 0.5f * w2, 0.f), 1.f);
        bool valid = (bi > 0) && (bv >= kMinConf);
        float4 bx; bx.x = oy1; bx.y = ox1; bx.z = oy2; bx.w = ox2;
        ((float4*)boxes)[wid] = bx;
        cls[wid] = valid ? bi : 0;
        if (valid) {
            int b = wid / NN, i = wid - b * NN;
            int cidx = bi - 1;
            int pos = atomicAdd(&ccnt[b * NCLS + cidx], 1);
            if (pos < MCLS)
                cslot[(size_t)(b * NCLS + cidx) * MCLS + pos] = mkey(bv, i);
        }
    }
}

// ---- kB: one 64-thread block per (batch,class), members direct from slots
// (no 2000-row scan). Sort + ballot-fixpoint greedy NMS (validated exact);
// kept rows write their u64 key into keysrc[row]. ----
__global__ void __launch_bounds__(64) kB_nms(
        const float* __restrict__ boxes,
        const int* __restrict__ ccnt,
        const unsigned long long* __restrict__ cslot,
        unsigned long long* __restrict__ keysrc) {
    const int p = blockIdx.x;
    const int b = p / NCLS;
    const int cidx = p % NCLS;
    const int l = threadIdx.x;

    __shared__ unsigned long long mk[MCLS];
    __shared__ float4 mbox[MCLS];

    const int cnt = min(ccnt[b * NCLS + cidx], MCLS);
    if (cnt == 0) return;
    const unsigned long long* slot = cslot + (size_t)(b * NCLS + cidx) * MCLS;
    const float4* bxs = (const float4*)boxes + (size_t)b * NN;

    unsigned long long va = (l < cnt) ? slot[l] : 0ull;
    unsigned long long vb = (64 + l < cnt) ? slot[64 + l] : 0ull;
    if (l < cnt) mk[l] = va;
    if (64 + l < cnt) mk[64 + l] = vb;
    int ra = 0, rb = 0;
    for (int t = 0; t < cnt; ++t) {
        unsigned long long kt = mk[t];
        ra += (kt > va);
        rb += (kt > vb);
    }
    if (l < cnt) mk[ra] = va;
    if (64 + l < cnt) mk[rb] = vb;

    for (int t = l; t < cnt; t += 64) {
        int i = (int)(~(unsigned int)mk[t]);
        mbox[t] = bxs[i];
    }

    unsigned long long kept0 = 0ull;
    {
        bool act = (l < cnt);
        float4 a = mbox[act ? l : 0];
        float aarea = (a.z - a.x) * (a.w - a.y);
        unsigned long long colmask = 0ull;
        int tend = min(64, cnt);
        for (int t = 0; t < tend; ++t) {
            float4 tb = mbox[t];
            if (t < l && act && iou_gt_thr(a, aarea, tb)) colmask |= (1ull << t);
        }
        unsigned long long kept = __ballot(act);
        while (true) {
            bool alive = act && ((colmask & kept) == 0ull);
            unsigned long long k2m = __ballot(alive);
            if (k2m == kept) break;
            kept = k2m;
        }
        kept0 = kept;
        bool alive = act && ((colmask & kept0) == 0ull);
        if (alive) {
            unsigned long long myk = mk[l];
            keysrc[(size_t)b * NN + (int)(~(unsigned int)myk)] = myk;
        }
    }
    if (cnt > 64) {
        int m = 64 + l;
        bool act = (m < cnt);
        float4 a = mbox[act ? m : 0];
        float aarea = (a.z - a.x) * (a.w - a.y);
        bool presup = false;
        for (int t = 0; t < 64; ++t) {
            if ((kept0 >> t) & 1ull) {
                if (act && iou_gt_thr(a, aarea, mbox[t])) presup = true;
            }
        }
        unsigned long long colmask = 0ull;
        for (int t = 64; t < cnt; ++t) {
            float4 tb = mbox[t];
            if ((t - 64) < l && act && iou_gt_thr(a, aarea, tb)) colmask |= (1ull << (t - 64));
        }
        bool pre = act && !presup;
        unsigned long long kept = __ballot(pre);
        while (true) {
            bool alive = pre && ((colmask & kept) == 0ull);
            unsigned long long k2m = __ballot(alive);
            if (k2m == kept) break;
            kept = k2m;
        }
        bool alive = pre && ((colmask & kept) == 0ull);
        if (alive) {
            unsigned long long myk = mk[64 + l];
            keysrc[(size_t)b * NN + (int)(~(unsigned int)myk)] = myk;
        }
    }
}

// ---- kC: 1 block per batch x 1024. Positional keys from keysrc (coalesced),
// histogram threshold, candidate rank-count, write. (R14-validated) ----
__global__ void __launch_bounds__(1024) kC_emit(
        const unsigned long long* __restrict__ keysrc,
        const float* __restrict__ boxes,
        const int* __restrict__ cls,
        float* __restrict__ out) {
    const int b = blockIdx.x;
    const int tid = threadIdx.x;
    const int wv = tid >> 6;
    const int l = tid & 63;

    __shared__ ulonglong2 keys2[1024];
    __shared__ ulonglong2 cand2[256];
    __shared__ int hist[256];
    __shared__ int Tcnt, tbsh, candn;
    unsigned long long* keys = (unsigned long long*)keys2;
    unsigned long long* cand = (unsigned long long*)cand2;

    if (tid < 256) hist[tid] = 0;
    if (tid < 48) keys[2000 + tid] = 0ull;
    if (tid == 0) { Tcnt = 0; candn = 0; }
    __syncthreads();

    const float4* bxs = (const float4*)boxes + (size_t)b * NN;

    for (int i = tid; i < NN; i += 1024) {
        unsigned long long kv = keysrc[(size_t)b * NN + i];
        keys[i] = kv;
        bool f = (kv != 0ull);
        if (f) atomicAdd(&hist[(int)((kv >> 47) & 0xFF)], 1);
        unsigned long long m = __ballot(f);
        if (l == 0 && m) atomicAdd(&Tcnt, __popcll(m));
    }
    __syncthreads();
    const int T = Tcnt;
    if (T == 0) return;                              // out pre-zeroed by kZ

    if (wv == 0) {
        int cum = 0, tb = 0, done = 0;
        for (int chunk = 3; chunk >= 0 && !done; --chunk) {
            int bkt = chunk * 64 + (63 - l);
            int s = hist[bkt];
            #pragma unroll
            for (int off = 1; off < 64; off <<= 1) {
                int o = __shfl_up(s, off);
                if (l >= off) s += o;
            }
            int chunktot = __shfl(s, 63);
            if (cum + chunktot >= MAXI) {
                unsigned long long m = __ballot(cum + s >= MAXI);
                int lane = __ffsll((long long)m) - 1;
                tb = chunk * 64 + (63 - lane);
                done = 1;
            } else {
                cum += chunktot;
            }
        }
        if (l == 0) tbsh = done ? tb : 0;
    }
    __syncthreads();
    const int tb = tbsh;

    for (int i = tid; i < NN; i += 1024) {
        unsigned long long kv = keys[i];
        bool pr = (kv != 0ull) && ((int)((kv >> 47) & 0xFF) >= tb);
        unsigned long long m = __ballot(pr);
        int basew = 0;
        if (l == 0 && m) basew = atomicAdd(&candn, __popcll(m));
        basew = __shfl(basew, 0);
        if (pr) {
            int pos = basew + __popcll(m & ((1ull << l) - 1ull));
            if (pos < 512) cand[pos] = kv;
        }
    }
    __syncthreads();
    const int nc = candn;
    if (tid == 0 && nc < 512) cand[nc] = 0ull;
    __syncthreads();

    if (nc <= 512) {
        const int np = (nc + 1) >> 1;
        for (int s = tid; s < nc; s += 1024) {
            unsigned long long myk = cand[s];
            int r = 0;
            for (int t = 0; t < np; ++t) {
                ulonglong2 kv = cand2[t];
                r += (int)(kv.x > myk);
                r += (int)(kv.y > myk);
            }
            if (r < MAXI) {
                int i = (int)(~(unsigned int)myk);
                float4 bx = bxs[i];
                float* o = out + ((size_t)b * MAXI + r) * 6;
                o[0] = bx.x; o[1] = bx.y; o[2] = bx.z; o[3] = bx.w;
                o[4] = (float)cls[(size_t)b * NN + i];
                o[5] = __uint_as_float((unsigned int)(myk >> 32));
            }
        }
    } else {
        for (int s = tid; s < NN; s += 1024) {
            unsigned long long myk = keys[s];
            if (myk == 0ull) continue;
            int r = 0;
            for (int t = 0; t < 1024; ++t) {
                ulonglong2 kv = keys2[t];
                r += (int)(kv.x > myk);
                r += (int)(kv.y > myk);
            }
            if (r < MAXI) {
                int i = (int)(~(unsigned int)myk);
                float4 bx = bxs[i];
                float* o = out + ((size_t)b * MAXI + r) * 6;
                o[0] = bx.x; o[1] = bx.y; o[2] = bx.z; o[3] = bx.w;
                o[4] = (float)cls[(size_t)b * NN + i];
                o[5] = __uint_as_float((unsigned int)(myk >> 32));
            }
        }
    }
}

extern "C" void kernel_launch(void* const* d_in, const int* in_sizes, int n_in,
                              void* d_out, int out_size, void* d_ws, size_t ws_size,
                              hipStream_t stream) {
    const float* rois   = (const float*)d_in[0];
    const float* probs  = (const float*)d_in[1];
    const float* deltas = (const float*)d_in[2];
    float* outp = (float*)d_out;

    char* ws = (char*)d_ws;
    float* boxes = (float*)(ws + 0);
    int*   cls   = (int*)  (ws + 256000);
    int*   ccnt  = (int*)  (ws + 320000);
    unsigned long long* cslot  = (unsigned long long*)(ws + 322560);
    unsigned long long* keysrc = (unsigned long long*)(ws + 977920);

    kZ_zero<<<1, 1024, 0, stream>>>(ccnt, outp);
    {
        int blocks = (BB * NN * 64) / 256;   // one wave per ROI, exact
        kA_refine<<<blocks, 256, 0, stream>>>(rois, probs, deltas, boxes, cls,
                                              ccnt, cslot, keysrc);
    }
    kB_nms<<<BB * NCLS, 64, 0, stream>>>(boxes, ccnt, cslot, keysrc);
    kC_emit<<<BB, 1024, 0, stream>>>(keysrc, boxes, cls, outp);
}

// Round 17
// 31.887 us; speedup vs baseline: 2.1383x; 1.4018x over previous
//
#include <hip/hip_runtime.h>
#include <math.h>

#define BB 8
#define NN 2000
#define CC 81
#define NCLS 80             // classes 1..80 (class 0 never valid)
#define MAXI 100
#define MCLS 128            // per-class member cap (mean ~25, sd ~5)
#define CPAD 16             // ints per counter: one 64B cacheline each
                            // (packed counters = 40 lines x 400-deep RMW serial
                            //  chains = ~25 us in kA; padded = ~25/line)

static constexpr float kMinConf = 0.7f;
static constexpr float kNmsThr  = 0.3f;

// ---------------- workspace layout (bytes) ----------------
// boxes  : [0,       256000)   BN*4 f32 (refined, clipped)
// cls    : [256000,  320000)   BN i32   (argmax class; 0 if invalid)
// ccnt   : [320000,  360960)   8*80*16 i32 padded counters (kZ zeroes)
// cslot  : [360960,  1016320)  8*80*128 u64 member keys (unordered; later
//                              rank-sorted on unique keys -> deterministic)
// keysrc : [1016320, 1144320)  BN u64 (kept key or 0; kA zeroes, kB writes)

// key = (score_bits << 32) | ~idx. Valid scores are positive floats so u32
// compare == float compare; key desc == (score desc, idx asc) == reference's
// stable descending argsort. idx = ~(u32)key. Keys unique; 0 = "absent".
__device__ __forceinline__ unsigned long long mkey(float s, int i) {
    return ((unsigned long long)__float_as_uint(s) << 32) | (unsigned int)(~(unsigned int)i);
}

__device__ __forceinline__ bool iou_gt_thr(float4 a, float aarea, float4 t) {
    float iy1 = fmaxf(a.x, t.x), ix1 = fmaxf(a.y, t.y);
    float iy2 = fminf(a.z, t.z), ix2 = fminf(a.w, t.w);
    float inter = fmaxf(iy2 - iy1, 0.f) * fmaxf(ix2 - ix1, 0.f);
    float tarea = (t.z - t.x) * (t.w - t.y);
    float uni = fmaxf(aarea + tarea - inter, 1e-12f);
    return inter > kNmsThr * uni;
}

// ---- kZ: zero padded ccnt and out (NEVER hipMemsetAsync in-graph: ~40us) ----
__global__ void __launch_bounds__(1024) kZ_zero(int* __restrict__ ccnt,
                                               float* __restrict__ out) {
    int tid = threadIdx.x;
    for (int i = tid; i < BB * NCLS * CPAD; i += 1024) ccnt[i] = 0;
    for (int i = tid; i < BB * MAXI * 6; i += 1024) out[i] = 0.f;
}

// ---- kA: wave-per-ROI argmax + box refine; valid ROIs bucket themselves into
// per-(batch,class) slots via CACHELINE-PADDED atomics; zeroes keysrc. ----
__global__ void kA_refine(const float* __restrict__ rois,
                          const float* __restrict__ probs,
                          const float* __restrict__ deltas,
                          float* __restrict__ boxes,
                          int* __restrict__ cls,
                          int* __restrict__ ccnt,
                          unsigned long long* __restrict__ cslot,
                          unsigned long long* __restrict__ keysrc) {
    int gtid = blockIdx.x * blockDim.x + threadIdx.x;
    if (gtid < BB * NN) keysrc[gtid] = 0ull;

    int wid = gtid >> 6;                // one wave per ROI
    int l = gtid & 63;

    const float* p = probs + (size_t)wid * CC;
    float v1 = p[l];                    // l < 64 < 81 always valid
    int   i1 = l;
    int   c2 = l + 64;
    float v2 = (c2 < CC) ? p[c2] : -1.0f;   // probs in [0,1)
    float bv; int bi;
    if (v2 > v1) { bv = v2; bi = c2; } else { bv = v1; bi = i1; }

    #pragma unroll
    for (int off = 32; off; off >>= 1) {
        float ov = __shfl_xor(bv, off);
        int   oi = __shfl_xor(bi, off);
        if (ov > bv || (ov == bv && oi < bi)) { bv = ov; bi = oi; }
    }

    if (l == 0) {
        const float4 dl = *(const float4*)(deltas + ((size_t)wid * CC + bi) * 4);
        float dy = dl.x * 0.1f, dx = dl.y * 0.1f, dh = dl.z * 0.2f, dw = dl.w * 0.2f;
        const float4 r = *(const float4*)(rois + (size_t)wid * 4);
        float y1 = r.x, x1 = r.y, y2 = r.z, x2 = r.w;
        float h = y2 - y1, w = x2 - x1;
        float cy = y1 + 0.5f * h + dy * h;
        float cx = x1 + 0.5f * w + dx * w;
        float h2 = h * expf(dh);
        float w2 = w * expf(dw);
        float oy1 = fminf(fmaxf(cy - 0.5f * h2, 0.f), 1.f);
        float ox1 = fminf(fmaxf(cx - 0.5f * w2, 0.f), 1.f);
        float oy2 = fminf(fmaxf(cy + 0.5f * h2, 0.f), 1.f);
        float ox2 = fminf(fmaxf(cx + 0.5f * w2, 0.f), 1.f);
        bool valid = (bi > 0) && (bv >= kMinConf);
        float4 bx; bx.x = oy1; bx.y = ox1; bx.z = oy2; bx.w = ox2;
        ((float4*)boxes)[wid] = bx;
        cls[wid] = valid ? bi : 0;
        if (valid) {
            int b = wid / NN, i = wid - b * NN;
            int cidx = bi - 1;
            int pos = atomicAdd(&ccnt[(b * NCLS + cidx) * CPAD], 1);
            if (pos < MCLS)
                cslot[(size_t)(b * NCLS + cidx) * MCLS + pos] = mkey(bv, i);
        }
    }
}

// ---- kB: one 64-thread block per (batch,class), members direct from slots
// (no 2000-row scan). Sort + ballot-fixpoint greedy NMS (validated exact);
// kept rows write their u64 key into keysrc[row]. (R16-validated) ----
__global__ void __launch_bounds__(64) kB_nms(
        const float* __restrict__ boxes,
        const int* __restrict__ ccnt,
        const unsigned long long* __restrict__ cslot,
        unsigned long long* __restrict__ keysrc) {
    const int p = blockIdx.x;
    const int b = p / NCLS;
    const int cidx = p % NCLS;
    const int l = threadIdx.x;

    __shared__ unsigned long long mk[MCLS];
    __shared__ float4 mbox[MCLS];

    const int cnt = min(ccnt[(b * NCLS + cidx) * CPAD], MCLS);
    if (cnt == 0) return;
    const unsigned long long* slot = cslot + (size_t)(b * NCLS + cidx) * MCLS;
    const float4* bxs = (const float4*)boxes + (size_t)b * NN;

    // load members (unordered) and in-wave stable rank sort by key desc
    unsigned long long va = (l < cnt) ? slot[l] : 0ull;
    unsigned long long vb = (64 + l < cnt) ? slot[64 + l] : 0ull;
    if (l < cnt) mk[l] = va;
    if (64 + l < cnt) mk[64 + l] = vb;
    int ra = 0, rb = 0;
    for (int t = 0; t < cnt; ++t) {
        unsigned long long kt = mk[t];               // uniform LDS broadcast
        ra += (kt > va);
        rb += (kt > vb);
    }
    if (l < cnt) mk[ra] = va;                        // lockstep: reads done
    if (64 + l < cnt) mk[rb] = vb;

    // fetch member boxes (sorted order)
    for (int t = l; t < cnt; t += 64) {
        int i = (int)(~(unsigned int)mk[t]);
        mbox[t] = bxs[i];
    }

    // chunk 0: ballot fixpoint == greedy (validated exact)
    unsigned long long kept0 = 0ull;
    {
        bool act = (l < cnt);
        float4 a = mbox[act ? l : 0];
        float aarea = (a.z - a.x) * (a.w - a.y);
        unsigned long long colmask = 0ull;
        int tend = min(64, cnt);
        for (int t = 0; t < tend; ++t) {
            float4 tb = mbox[t];                     // uniform LDS broadcast
            if (t < l && act && iou_gt_thr(a, aarea, tb)) colmask |= (1ull << t);
        }
        unsigned long long kept = __ballot(act);
        while (true) {
            bool alive = act && ((colmask & kept) == 0ull);
            unsigned long long k2m = __ballot(alive);
            if (k2m == kept) break;
            kept = k2m;
        }
        kept0 = kept;
        bool alive = act && ((colmask & kept0) == 0ull);
        if (alive) {
            unsigned long long myk = mk[l];
            keysrc[(size_t)b * NN + (int)(~(unsigned int)myk)] = myk;
        }
    }
    // chunk 1 (members 64..cnt-1): rare
    if (cnt > 64) {
        int m = 64 + l;
        bool act = (m < cnt);
        float4 a = mbox[act ? m : 0];
        float aarea = (a.z - a.x) * (a.w - a.y);
        bool presup = false;
        for (int t = 0; t < 64; ++t) {
            if ((kept0 >> t) & 1ull) {
                if (act && iou_gt_thr(a, aarea, mbox[t])) presup = true;
            }
        }
        unsigned long long colmask = 0ull;
        for (int t = 64; t < cnt; ++t) {
            float4 tb = mbox[t];
            if ((t - 64) < l && act && iou_gt_thr(a, aarea, tb)) colmask |= (1ull << (t - 64));
        }
        bool pre = act && !presup;
        unsigned long long kept = __ballot(pre);
        while (true) {
            bool alive = pre && ((colmask & kept) == 0ull);
            unsigned long long k2m = __ballot(alive);
            if (k2m == kept) break;
            kept = k2m;
        }
        bool alive = pre && ((colmask & kept) == 0ull);
        if (alive) {
            unsigned long long myk = mk[64 + l];
            keysrc[(size_t)b * NN + (int)(~(unsigned int)myk)] = myk;
        }
    }
}

// ---- kC: 1 block per batch x 1024. Positional keys from keysrc (coalesced),
// histogram threshold, candidate rank-count, write. (R14/R16-validated) ----
__global__ void __launch_bounds__(1024) kC_emit(
        const unsigned long long* __restrict__ keysrc,
        const float* __restrict__ boxes,
        const int* __restrict__ cls,
        float* __restrict__ out) {
    const int b = blockIdx.x;
    const int tid = threadIdx.x;
    const int wv = tid >> 6;
    const int l = tid & 63;

    __shared__ ulonglong2 keys2[1024];               // 16 KB (positional by row)
    __shared__ ulonglong2 cand2[256];                //  4 KB
    __shared__ int hist[256];
    __shared__ int Tcnt, tbsh, candn;
    unsigned long long* keys = (unsigned long long*)keys2;
    unsigned long long* cand = (unsigned long long*)cand2;

    if (tid < 256) hist[tid] = 0;
    if (tid < 48) keys[2000 + tid] = 0ull;           // pad tail
    if (tid == 0) { Tcnt = 0; candn = 0; }
    __syncthreads();

    const float4* bxs = (const float4*)boxes + (size_t)b * NN;

    for (int i = tid; i < NN; i += 1024) {
        unsigned long long kv = keysrc[(size_t)b * NN + i];
        keys[i] = kv;
        bool f = (kv != 0ull);
        if (f) atomicAdd(&hist[(int)((kv >> 47) & 0xFF)], 1);
        unsigned long long m = __ballot(f);
        if (l == 0 && m) atomicAdd(&Tcnt, __popcll(m));
    }
    __syncthreads();
    const int T = Tcnt;
    if (T == 0) return;                              // out pre-zeroed by kZ

    // wave 0: threshold bucket tb (kept scores in [0.7,1) -> fixed exponent ->
    // bucket (key>>47)&0xFF monotone in score)
    if (wv == 0) {
        int cum = 0, tb = 0, done = 0;
        for (int chunk = 3; chunk >= 0 && !done; --chunk) {
            int bkt = chunk * 64 + (63 - l);         // lane 0 = highest bucket
            int s = hist[bkt];
            #pragma unroll
            for (int off = 1; off < 64; off <<= 1) {
                int o = __shfl_up(s, off);
                if (l >= off) s += o;
            }
            int chunktot = __shfl(s, 63);
            if (cum + chunktot >= MAXI) {
                unsigned long long m = __ballot(cum + s >= MAXI);
                int lane = __ffsll((long long)m) - 1;
                tb = chunk * 64 + (63 - lane);
                done = 1;
            } else {
                cum += chunktot;
            }
        }
        if (l == 0) tbsh = done ? tb : 0;            // T<100 -> all buckets
    }
    __syncthreads();
    const int tb = tbsh;

    // compact candidates (bucket >= tb); rank among candidates == global rank
    for (int i = tid; i < NN; i += 1024) {
        unsigned long long kv = keys[i];
        bool pr = (kv != 0ull) && ((int)((kv >> 47) & 0xFF) >= tb);
        unsigned long long m = __ballot(pr);
        int basew = 0;
        if (l == 0 && m) basew = atomicAdd(&candn, __popcll(m));
        basew = __shfl(basew, 0);
        if (pr) {
            int pos = basew + __popcll(m & ((1ull << l) - 1ull));
            if (pos < 512) cand[pos] = kv;
        }
    }
    __syncthreads();
    const int nc = candn;
    if (tid == 0 && nc < 512) cand[nc] = 0ull;       // pad for pair read
    __syncthreads();

    if (nc <= 512) {
        const int np = (nc + 1) >> 1;
        for (int s = tid; s < nc; s += 1024) {
            unsigned long long myk = cand[s];
            int r = 0;
            for (int t = 0; t < np; ++t) {
                ulonglong2 kv = cand2[t];
                r += (int)(kv.x > myk);
                r += (int)(kv.y > myk);              // pad 0 never counts
            }
            if (r < MAXI) {
                int i = (int)(~(unsigned int)myk);
                float4 bx = bxs[i];
                float* o = out + ((size_t)b * MAXI + r) * 6;
                o[0] = bx.x; o[1] = bx.y; o[2] = bx.z; o[3] = bx.w;
                o[4] = (float)cls[(size_t)b * NN + i];
                o[5] = __uint_as_float((unsigned int)(myk >> 32));
            }
        }
    } else {
        // pathological fallback: rank over all rows (zeros excluded)
        for (int s = tid; s < NN; s += 1024) {
            unsigned long long myk = keys[s];
            if (myk == 0ull) continue;
            int r = 0;
            for (int t = 0; t < 1024; ++t) {
                ulonglong2 kv = keys2[t];
                r += (int)(kv.x > myk);
                r += (int)(kv.y > myk);
            }
            if (r < MAXI) {
                int i = (int)(~(unsigned int)myk);
                float4 bx = bxs[i];
                float* o = out + ((size_t)b * MAXI + r) * 6;
                o[0] = bx.x; o[1] = bx.y; o[2] = bx.z; o[3] = bx.w;
                o[4] = (float)cls[(size_t)b * NN + i];
                o[5] = __uint_as_float((unsigned int)(myk >> 32));
            }
        }
    }
}

extern "C" void kernel_launch(void* const* d_in, const int* in_sizes, int n_in,
                              void* d_out, int out_size, void* d_ws, size_t ws_size,
                              hipStream_t stream) {
    const float* rois   = (const float*)d_in[0];
    const float* probs  = (const float*)d_in[1];
    const float* deltas = (const float*)d_in[2];
    float* outp = (float*)d_out;

    char* ws = (char*)d_ws;
    float* boxes = (float*)(ws + 0);
    int*   cls   = (int*)  (ws + 256000);
    int*   ccnt  = (int*)  (ws + 320000);
    unsigned long long* cslot  = (unsigned long long*)(ws + 360960);
    unsigned long long* keysrc = (unsigned long long*)(ws + 1016320);

    kZ_zero<<<1, 1024, 0, stream>>>(ccnt, outp);
    {
        int blocks = (BB * NN * 64) / 256;   // one wave per ROI, exact
        kA_refine<<<blocks, 256, 0, stream>>>(rois, probs, deltas, boxes, cls,
                                              ccnt, cslot, keysrc);
    }
    kB_nms<<<BB * NCLS, 64, 0, stream>>>(boxes, ccnt, cslot, keysrc);
    kC_emit<<<BB, 1024, 0, stream>>>(keysrc, boxes, cls, outp);
}

// Round 18
// 29.102 us; speedup vs baseline: 2.3429x; 1.0957x over previous
//
#include <hip/hip_runtime.h>
#include <math.h>

#define BB 8
#define NN 2000
#define CC 81
#define NCLS 80             // classes 1..80 (class 0 never valid)
#define MAXI 100
#define MCLS 128            // per-class member cap (mean ~25, sd ~5)

static constexpr float kMinConf = 0.7f;
static constexpr float kNmsThr  = 0.3f;

// ---------------- workspace layout (bytes) ----------------
// boxes  : [0,       256000)   BN*4 f32 (refined, clipped)
// sc     : [256000,  320000)   BN f32   (raw max score)
// cls    : [320000,  384000)   BN i32   (argmax class; 0 if invalid)
// ccnt   : [384000,  386560)   8*80 i32 member counts (written plain by kB0)
// cslot  : [386560,  1041920)  8*80*128 u64 member keys (unordered; later
//                              rank-sorted on unique keys -> deterministic)
// keysrc : [1041920, 1169920)  BN u64 (kept key or 0; kA zeroes, kB1 writes)

// key = (score_bits << 32) | ~idx. Valid scores are positive floats so u32
// compare == float compare; key desc == (score desc, idx asc) == reference's
// stable descending argsort. idx = ~(u32)key. Keys unique; 0 = "absent".
__device__ __forceinline__ unsigned long long mkey(float s, int i) {
    return ((unsigned long long)__float_as_uint(s) << 32) | (unsigned int)(~(unsigned int)i);
}

__device__ __forceinline__ bool iou_gt_thr(float4 a, float aarea, float4 t) {
    float iy1 = fmaxf(a.x, t.x), ix1 = fmaxf(a.y, t.y);
    float iy2 = fminf(a.z, t.z), ix2 = fminf(a.w, t.w);
    float inter = fmaxf(iy2 - iy1, 0.f) * fmaxf(ix2 - ix1, 0.f);
    float tarea = (t.z - t.x) * (t.w - t.y);
    float uni = fmaxf(aarea + tarea - inter, 1e-12f);
    return inter > kNmsThr * uni;
}

// ---- kA: wave-per-ROI argmax + box refine; zero out[] and keysrc[].
// NO atomics anywhere. (R14-validated core) ----
__global__ void kA_refine(const float* __restrict__ rois,
                          const float* __restrict__ probs,
                          const float* __restrict__ deltas,
                          float* __restrict__ boxes,
                          float* __restrict__ sc,
                          int* __restrict__ cls,
                          unsigned long long* __restrict__ keysrc,
                          float* __restrict__ outz) {
    int gtid = blockIdx.x * blockDim.x + threadIdx.x;
    if (gtid < BB * MAXI * 6) outz[gtid] = 0.f;      // pre-zero output
    if (gtid < BB * NN) keysrc[gtid] = 0ull;         // zero kept-key array

    int wid = gtid >> 6;                // one wave per ROI
    int l = gtid & 63;

    const float* p = probs + (size_t)wid * CC;
    float v1 = p[l];                    // l < 64 < 81 always valid
    int   i1 = l;
    int   c2 = l + 64;
    float v2 = (c2 < CC) ? p[c2] : -1.0f;   // probs in [0,1)
    float bv; int bi;
    if (v2 > v1) { bv = v2; bi = c2; } else { bv = v1; bi = i1; }

    #pragma unroll
    for (int off = 32; off; off >>= 1) {
        float ov = __shfl_xor(bv, off);
        int   oi = __shfl_xor(bi, off);
        if (ov > bv || (ov == bv && oi < bi)) { bv = ov; bi = oi; }
    }

    if (l == 0) {
        const float4 dl = *(const float4*)(deltas + ((size_t)wid * CC + bi) * 4);
        float dy = dl.x * 0.1f, dx = dl.y * 0.1f, dh = dl.z * 0.2f, dw = dl.w * 0.2f;
        const float4 r = *(const float4*)(rois + (size_t)wid * 4);
        float y1 = r.x, x1 = r.y, y2 = r.z, x2 = r.w;
        float h = y2 - y1, w = x2 - x1;
        float cy = y1 + 0.5f * h + dy * h;
        float cx = x1 + 0.5f * w + dx * w;
        float h2 = h * expf(dh);
        float w2 = w * expf(dw);
        float oy1 = fminf(fmaxf(cy - 0.5f * h2, 0.f), 1.f);
        float ox1 = fminf(fmaxf(cx - 0.5f * w2, 0.f), 1.f);
        float oy2 = fminf(fmaxf(cy + 0.5f * h2, 0.f), 1.f);
        float ox2 = fminf(fmaxf(cx + 0.5f * w2, 0.f), 1.f);
        bool valid = (bi > 0) && (bv >= kMinConf);
        float4 bx; bx.x = oy1; bx.y = ox1; bx.z = oy2; bx.w = ox2;
        ((float4*)boxes)[wid] = bx;
        sc[wid] = bv;
        cls[wid] = valid ? bi : 0;      // cls==0 encodes "invalid"
    }
}

// ---- kB0: one block per batch; ONE scan of the 2000 rows partitions them
// into 80 per-class slot lists via LDS atomics (in-CU, ~30cy — not global
// RMWs). Final counts stored with plain writes. Slot order nondeterministic;
// erased by kB1's unique-key sort. ----
__global__ void __launch_bounds__(1024) kB0_bucket(
        const float* __restrict__ sc,
        const int* __restrict__ cls,
        int* __restrict__ ccnt,
        unsigned long long* __restrict__ cslot) {
    const int b = blockIdx.x;
    const int tid = threadIdx.x;
    __shared__ int lcnt[NCLS];

    if (tid < NCLS) lcnt[tid] = 0;
    __syncthreads();

    for (int i = tid; i < NN; i += 1024) {
        int c = cls[(size_t)b * NN + i];             // coalesced
        if (c > 0) {
            int pos = atomicAdd(&lcnt[c - 1], 1);    // LDS atomic
            if (pos < MCLS)
                cslot[(size_t)(b * NCLS + (c - 1)) * MCLS + pos] =
                    mkey(sc[(size_t)b * NN + i], i);
        }
    }
    __syncthreads();
    if (tid < NCLS) ccnt[b * NCLS + tid] = lcnt[tid];   // plain store
}

// ---- kB1: one 64-thread block per (batch,class), members direct from slots.
// In-wave rank sort + ballot-fixpoint greedy NMS (validated exact); kept rows
// write their u64 key into keysrc[row]. (R17-validated) ----
__global__ void __launch_bounds__(64) kB1_nms(
        const float* __restrict__ boxes,
        const int* __restrict__ ccnt,
        const unsigned long long* __restrict__ cslot,
        unsigned long long* __restrict__ keysrc) {
    const int p = blockIdx.x;
    const int b = p / NCLS;
    const int cidx = p % NCLS;
    const int l = threadIdx.x;

    __shared__ unsigned long long mk[MCLS];
    __shared__ float4 mbox[MCLS];

    const int cnt = min(ccnt[b * NCLS + cidx], MCLS);
    if (cnt == 0) return;
    const unsigned long long* slot = cslot + (size_t)(b * NCLS + cidx) * MCLS;
    const float4* bxs = (const float4*)boxes + (size_t)b * NN;

    // load members (unordered) and in-wave stable rank sort by key desc
    unsigned long long va = (l < cnt) ? slot[l] : 0ull;
    unsigned long long vb = (64 + l < cnt) ? slot[64 + l] : 0ull;
    if (l < cnt) mk[l] = va;
    if (64 + l < cnt) mk[64 + l] = vb;
    int ra = 0, rb = 0;
    for (int t = 0; t < cnt; ++t) {
        unsigned long long kt = mk[t];               // uniform LDS broadcast
        ra += (kt > va);
        rb += (kt > vb);
    }
    if (l < cnt) mk[ra] = va;                        // lockstep: reads done
    if (64 + l < cnt) mk[rb] = vb;

    // fetch member boxes (sorted order)
    for (int t = l; t < cnt; t += 64) {
        int i = (int)(~(unsigned int)mk[t]);
        mbox[t] = bxs[i];
    }

    // chunk 0: ballot fixpoint == greedy (validated exact)
    unsigned long long kept0 = 0ull;
    {
        bool act = (l < cnt);
        float4 a = mbox[act ? l : 0];
        float aarea = (a.z - a.x) * (a.w - a.y);
        unsigned long long colmask = 0ull;
        int tend = min(64, cnt);
        for (int t = 0; t < tend; ++t) {
            float4 tb = mbox[t];                     // uniform LDS broadcast
            if (t < l && act && iou_gt_thr(a, aarea, tb)) colmask |= (1ull << t);
        }
        unsigned long long kept = __ballot(act);
        while (true) {
            bool alive = act && ((colmask & kept) == 0ull);
            unsigned long long k2m = __ballot(alive);
            if (k2m == kept) break;
            kept = k2m;
        }
        kept0 = kept;
        bool alive = act && ((colmask & kept0) == 0ull);
        if (alive) {
            unsigned long long myk = mk[l];
            keysrc[(size_t)b * NN + (int)(~(unsigned int)myk)] = myk;
        }
    }
    // chunk 1 (members 64..cnt-1): rare
    if (cnt > 64) {
        int m = 64 + l;
        bool act = (m < cnt);
        float4 a = mbox[act ? m : 0];
        float aarea = (a.z - a.x) * (a.w - a.y);
        bool presup = false;
        for (int t = 0; t < 64; ++t) {
            if ((kept0 >> t) & 1ull) {
                if (act && iou_gt_thr(a, aarea, mbox[t])) presup = true;
            }
        }
        unsigned long long colmask = 0ull;
        for (int t = 64; t < cnt; ++t) {
            float4 tb = mbox[t];
            if ((t - 64) < l && act && iou_gt_thr(a, aarea, tb)) colmask |= (1ull << (t - 64));
        }
        bool pre = act && !presup;
        unsigned long long kept = __ballot(pre);
        while (true) {
            bool alive = pre && ((colmask & kept) == 0ull);
            unsigned long long k2m = __ballot(alive);
            if (k2m == kept) break;
            kept = k2m;
        }
        bool alive = pre && ((colmask & kept) == 0ull);
        if (alive) {
            unsigned long long myk = mk[64 + l];
            keysrc[(size_t)b * NN + (int)(~(unsigned int)myk)] = myk;
        }
    }
}

// ---- kC: 1 block per batch x 1024. Positional keys from keysrc (coalesced),
// histogram threshold, candidate rank-count, write. (R14/R17-validated) ----
__global__ void __launch_bounds__(1024) kC_emit(
        const unsigned long long* __restrict__ keysrc,
        const float* __restrict__ boxes,
        const int* __restrict__ cls,
        float* __restrict__ out) {
    const int b = blockIdx.x;
    const int tid = threadIdx.x;
    const int wv = tid >> 6;
    const int l = tid & 63;

    __shared__ ulonglong2 keys2[1024];               // 16 KB (positional by row)
    __shared__ ulonglong2 cand2[256];                //  4 KB
    __shared__ int hist[256];
    __shared__ int Tcnt, tbsh, candn;
    unsigned long long* keys = (unsigned long long*)keys2;
    unsigned long long* cand = (unsigned long long*)cand2;

    if (tid < 256) hist[tid] = 0;
    if (tid < 48) keys[2000 + tid] = 0ull;           // pad tail
    if (tid == 0) { Tcnt = 0; candn = 0; }
    __syncthreads();

    const float4* bxs = (const float4*)boxes + (size_t)b * NN;

    for (int i = tid; i < NN; i += 1024) {
        unsigned long long kv = keysrc[(size_t)b * NN + i];
        keys[i] = kv;
        bool f = (kv != 0ull);
        if (f) atomicAdd(&hist[(int)((kv >> 47) & 0xFF)], 1);
        unsigned long long m = __ballot(f);
        if (l == 0 && m) atomicAdd(&Tcnt, __popcll(m));
    }
    __syncthreads();
    const int T = Tcnt;
    if (T == 0) return;                              // out pre-zeroed by kA

    // wave 0: threshold bucket tb (kept scores in [0.7,1) -> fixed exponent ->
    // bucket (key>>47)&0xFF monotone in score)
    if (wv == 0) {
        int cum = 0, tb = 0, done = 0;
        for (int chunk = 3; chunk >= 0 && !done; --chunk) {
            int bkt = chunk * 64 + (63 - l);         // lane 0 = highest bucket
            int s = hist[bkt];
            #pragma unroll
            for (int off = 1; off < 64; off <<= 1) {
                int o = __shfl_up(s, off);
                if (l >= off) s += o;
            }
            int chunktot = __shfl(s, 63);
            if (cum + chunktot >= MAXI) {
                unsigned long long m = __ballot(cum + s >= MAXI);
                int lane = __ffsll((long long)m) - 1;
                tb = chunk * 64 + (63 - lane);
                done = 1;
            } else {
                cum += chunktot;
            }
        }
        if (l == 0) tbsh = done ? tb : 0;            // T<100 -> all buckets
    }
    __syncthreads();
    const int tb = tbsh;

    // compact candidates (bucket >= tb); rank among candidates == global rank
    for (int i = tid; i < NN; i += 1024) {
        unsigned long long kv = keys[i];
        bool pr = (kv != 0ull) && ((int)((kv >> 47) & 0xFF) >= tb);
        unsigned long long m = __ballot(pr);
        int basew = 0;
        if (l == 0 && m) basew = atomicAdd(&candn, __popcll(m));
        basew = __shfl(basew, 0);
        if (pr) {
            int pos = basew + __popcll(m & ((1ull << l) - 1ull));
            if (pos < 512) cand[pos] = kv;
        }
    }
    __syncthreads();
    const int nc = candn;
    if (tid == 0 && nc < 512) cand[nc] = 0ull;       // pad for pair read
    __syncthreads();

    if (nc <= 512) {
        const int np = (nc + 1) >> 1;
        for (int s = tid; s < nc; s += 1024) {
            unsigned long long myk = cand[s];
            int r = 0;
            for (int t = 0; t < np; ++t) {
                ulonglong2 kv = cand2[t];
                r += (int)(kv.x > myk);
                r += (int)(kv.y > myk);              // pad 0 never counts
            }
            if (r < MAXI) {
                int i = (int)(~(unsigned int)myk);
                float4 bx = bxs[i];
                float* o = out + ((size_t)b * MAXI + r) * 6;
                o[0] = bx.x; o[1] = bx.y; o[2] = bx.z; o[3] = bx.w;
                o[4] = (float)cls[(size_t)b * NN + i];
                o[5] = __uint_as_float((unsigned int)(myk >> 32));
            }
        }
    } else {
        // pathological fallback: rank over all rows (zeros excluded)
        for (int s = tid; s < NN; s += 1024) {
            unsigned long long myk = keys[s];
            if (myk == 0ull) continue;
            int r = 0;
            for (int t = 0; t < 1024; ++t) {
                ulonglong2 kv = keys2[t];
                r += (int)(kv.x > myk);
                r += (int)(kv.y > myk);
            }
            if (r < MAXI) {
                int i = (int)(~(unsigned int)myk);
                float4 bx = bxs[i];
                float* o = out + ((size_t)b * MAXI + r) * 6;
                o[0] = bx.x; o[1] = bx.y; o[2] = bx.z; o[3] = bx.w;
                o[4] = (float)cls[(size_t)b * NN + i];
                o[5] = __uint_as_float((unsigned int)(myk >> 32));
            }
        }
    }
}

extern "C" void kernel_launch(void* const* d_in, const int* in_sizes, int n_in,
                              void* d_out, int out_size, void* d_ws, size_t ws_size,
                              hipStream_t stream) {
    const float* rois   = (const float*)d_in[0];
    const float* probs  = (const float*)d_in[1];
    const float* deltas = (const float*)d_in[2];
    float* outp = (float*)d_out;

    char* ws = (char*)d_ws;
    float* boxes = (float*)(ws + 0);
    float* sc    = (float*)(ws + 256000);
    int*   cls   = (int*)  (ws + 320000);
    int*   ccnt  = (int*)  (ws + 384000);
    unsigned long long* cslot  = (unsigned long long*)(ws + 386560);
    unsigned long long* keysrc = (unsigned long long*)(ws + 1041920);

    {
        int blocks = (BB * NN * 64) / 256;   // one wave per ROI, exact
        kA_refine<<<blocks, 256, 0, stream>>>(rois, probs, deltas, boxes, sc,
                                              cls, keysrc, outp);
    }
    kB0_bucket<<<BB, 1024, 0, stream>>>(sc, cls, ccnt, cslot);
    kB1_nms<<<BB * NCLS, 64, 0, stream>>>(boxes, ccnt, cslot, keysrc);
    kC_emit<<<BB, 1024, 0, stream>>>(keysrc, boxes, cls, outp);
}